// Round 1
// 229.226 us; speedup vs baseline: 1.0324x; 1.0324x over previous
//
#include <hip/hip_runtime.h>
#include <hip/hip_bf16.h>

typedef __attribute__((ext_vector_type(8))) short short8;
typedef __attribute__((ext_vector_type(4))) short short4v;
typedef __attribute__((ext_vector_type(4))) float f32x4;

__device__ __forceinline__ unsigned short f2bf(float f) {
    __hip_bfloat16 h = __float2bfloat16(f);
    unsigned short u;
    __builtin_memcpy(&u, &h, 2);
    return u;
}
// packed RNE f32->bf16 pairs: compiles to v_cvt_pk_bf16_f32 (same rounding as
// the scalar path, ~1/4 the VALU instructions)
__device__ __forceinline__ short4v pack4bf(float a, float b, float c, float d) {
    union { __hip_bfloat162 h[2]; short4v s; } r;
    r.h[0] = __float22bfloat162_rn(make_float2(a, b));
    r.h[1] = __float22bfloat162_rn(make_float2(c, d));
    return r.s;
}

#define GLD16(gp, lp) __builtin_amdgcn_global_load_lds( \
    (const __attribute__((address_space(1))) void*)(gp), \
    (__attribute__((address_space(3))) void*)(lp), 16, 0, 0)

// ---------------------------------------------------------------------------
// prep: fused f32->bf16 convert of q,k,v (blocks 0..6143) + weight transpose
// (blocks 6144..7167). One launch instead of two.
// ---------------------------------------------------------------------------
__global__ __launch_bounds__(256) void prep(
    const float* __restrict__ q, const float* __restrict__ k, const float* __restrict__ v,
    unsigned short* __restrict__ qb, unsigned short* __restrict__ kb, unsigned short* __restrict__ vb,
    const float* __restrict__ W0, const float* __restrict__ W1,
    const float* __restrict__ W2, const float* __restrict__ W3,
    unsigned short* __restrict__ T0, unsigned short* __restrict__ T1,
    unsigned short* __restrict__ T2, unsigned short* __restrict__ T3)
{
    __shared__ unsigned short Ts[64 * 72];
    int bx = blockIdx.x;
    if (bx < 6144) {
        const float* src; unsigned short* dst;
        switch (bx >> 11) { case 0: src = q; dst = qb; break;
                            case 1: src = k; dst = kb; break;
                            default: src = v; dst = vb; break; }
        size_t i = ((size_t)(bx & 2047) * 256 + threadIdx.x) * 8;
        float4 x0 = *(const float4*)&src[i];
        float4 x1 = *(const float4*)&src[i + 4];
        union { unsigned short s[8]; uint4 u; } p;
        p.s[0] = f2bf(x0.x); p.s[1] = f2bf(x0.y); p.s[2] = f2bf(x0.z); p.s[3] = f2bf(x0.w);
        p.s[4] = f2bf(x1.x); p.s[5] = f2bf(x1.y); p.s[6] = f2bf(x1.z); p.s[7] = f2bf(x1.w);
        *(uint4*)&dst[i] = p.u;
        return;
    }
    int w = bx - 6144;                // 1024 blocks: z(4) x kx(16) x ny(16)
    int z = w >> 8, rem = w & 255;
    int kx = rem >> 4, ny = rem & 15;
    const float* W;
    unsigned short* T;
    switch (z) {
        case 0: W = W0; T = T0; break;
        case 1: W = W1; T = T1; break;
        case 2: W = W2; T = T2; break;
        default: W = W3; T = T3; break;
    }
    int tid = threadIdx.x;
    int c = tid & 7, r = tid >> 3;
    int k0 = kx * 64, n0 = ny * 64;
    for (int i = 0; i < 64; i += 32) {
        const float* src = &W[(size_t)(k0 + r + i) * 1024 + n0 + c * 8];
        float4 x0 = *(const float4*)src;
        float4 x1 = *(const float4*)(src + 4);
        unsigned short* d = &Ts[(r + i) * 72 + c * 8];
        d[0] = f2bf(x0.x); d[1] = f2bf(x0.y); d[2] = f2bf(x0.z); d[3] = f2bf(x0.w);
        d[4] = f2bf(x1.x); d[5] = f2bf(x1.y); d[6] = f2bf(x1.z); d[7] = f2bf(x1.w);
    }
    __syncthreads();
    for (int i = 0; i < 64; i += 32) {
        union { unsigned short s[8]; uint4 v; } u;
        for (int j = 0; j < 8; j++) u.s[j] = Ts[(c * 8 + j) * 72 + (r + i)];
        *(uint4*)&T[(size_t)(n0 + r + i) * 1024 + k0 + c * 8] = u.v;
    }
}

// ---------------------------------------------------------------------------
// GEMM core v3: 128x128 tile, BK=32, single-buffered global_load_lds staging
// (r7's dbuf regressed ~10us: compiler can't disambiguate buf halves and
// serializes prefetch->ds_read) + XOR-swizzled LDS to kill the 8-way bank
// conflict of 64B rows: lane l fetches global chunk (l&3)^((l>>3)&3), so row
// R's chunk g lives at position g^((R>>1)&3); fragment read position =
// quad^((lm>>1)&3). Phase banks: 8 distinct starts -> 2-way = free.
// mode 0: f32 row-major [4096][1024]; mode 1: bf16 [bh][t][d] scatter;
// mode 2: bf16 [bh][d][t] scatter (packed 8B stores).
// ---------------------------------------------------------------------------
__device__ __forceinline__ void gemm_core(
    const unsigned short* __restrict__ A, const unsigned short* __restrict__ BT,
    const float* __restrict__ bias, void* __restrict__ outv,
    int mode, float scale)
{
    const int K = 1024;
    __shared__ unsigned short As[128 * 32];
    __shared__ unsigned short Bs[128 * 32];
    int tid = threadIdx.x;
    int m0 = blockIdx.x * 128, n0 = blockIdx.y * 128;
    int lane = tid & 63, wave = tid >> 6;
    int lm = lane & 15, quad = lane >> 4;
    int wm = (wave >> 1) * 64, wn = (wave & 1) * 64;

    // staging: lane l -> row wave*32 + l/4 (and +16), swizzled chunk fetch
    int lrow = lane >> 2;
    int scol = ((lane & 3) ^ ((lane >> 3) & 3)) * 8;
    const unsigned short* Ag = A + (size_t)(m0 + wave * 32 + lrow) * K + scol;
    const unsigned short* Bg = BT + (size_t)(n0 + wave * 32 + lrow) * K + scol;
    unsigned short* AsW0 = &As[(wave * 32) * 32];
    unsigned short* AsW1 = &As[(wave * 32 + 16) * 32];
    unsigned short* BsW0 = &Bs[(wave * 32) * 32];
    unsigned short* BsW1 = &Bs[(wave * 32 + 16) * 32];

    // fragment read: chunk quad of row R at position quad^((lm>>1)&3)
    int rpos = (quad ^ ((lm >> 1) & 3)) * 8;

    f32x4 acc[4][4];
    for (int i = 0; i < 4; i++)
        for (int j = 0; j < 4; j++)
            for (int r = 0; r < 4; r++) acc[i][j][r] = 0.0f;

    for (int kb = 0; kb < K; kb += 32) {
        GLD16(Ag, AsW0);
        GLD16(Ag + 16 * K, AsW1);
        GLD16(Bg, BsW0);
        GLD16(Bg + 16 * K, BsW1);
        Ag += 32; Bg += 32;
        __syncthreads();
        short8 a[4], b[4];
        for (int i = 0; i < 4; i++)
            a[i] = *(const short8*)&As[(wm + i * 16 + lm) * 32 + rpos];
        for (int j = 0; j < 4; j++)
            b[j] = *(const short8*)&Bs[(wn + j * 16 + lm) * 32 + rpos];
        for (int i = 0; i < 4; i++)
            for (int j = 0; j < 4; j++)
                acc[i][j] = __builtin_amdgcn_mfma_f32_16x16x32_bf16(a[i], b[j], acc[i][j], 0, 0, 0);
        __syncthreads();
    }

    for (int j = 0; j < 4; j++) {
        int col = n0 + wn + j * 16 + lm;
        float bv = bias[col];
        for (int i = 0; i < 4; i++) {
            int rowb = m0 + wm + i * 16 + quad * 4;
            if (mode == 0) {
                float* out32 = (float*)outv;
                for (int r = 0; r < 4; r++)
                    out32[(size_t)(rowb + r) * 1024 + col] = (acc[i][j][r] + bv) * scale;
            } else if (mode == 1) {
                unsigned short* out16 = (unsigned short*)outv;
                int h = col >> 6, d = col & 63;
                int bb = rowb >> 11, t = rowb & 2047;
                size_t base = (((size_t)(bb * 16 + h)) * 2048 + t) * 64 + d;
                for (int r = 0; r < 4; r++)
                    out16[base + (size_t)r * 64] = f2bf((acc[i][j][r] + bv) * scale);
            } else {
                unsigned short* out16 = (unsigned short*)outv;
                int h = col >> 6, d = col & 63;
                int bb = rowb >> 11, t = rowb & 2047;   // t is 4-aligned
                ushort4 pk;
                pk.x = f2bf((acc[i][j][0] + bv) * scale);
                pk.y = f2bf((acc[i][j][1] + bv) * scale);
                pk.z = f2bf((acc[i][j][2] + bv) * scale);
                pk.w = f2bf((acc[i][j][3] + bv) * scale);
                *(ushort4*)&out16[(((size_t)(bb * 16 + h)) * 64 + d) * 2048 + t] = pk;
            }
        }
    }
}

// Fused QKV projections: blockIdx.z selects {q,k,v}; 768 blocks = 3/CU.
// Q scale folds 1/sqrt(64) * log2(e) so attention can use exp2 natively.
__global__ __launch_bounds__(256) void qkv_gemm(
    const unsigned short* __restrict__ qbf, const unsigned short* __restrict__ kbf,
    const unsigned short* __restrict__ vbf,
    const unsigned short* __restrict__ WqT, const unsigned short* __restrict__ WkT,
    const unsigned short* __restrict__ WvT,
    const float* __restrict__ bq, const float* __restrict__ bk, const float* __restrict__ bv,
    unsigned short* __restrict__ Qh, unsigned short* __restrict__ Kh,
    unsigned short* __restrict__ VhT)
{
    switch (blockIdx.z) {
        case 0:  gemm_core(qbf, WqT, bq, Qh,  1, 0.18033688011f); break; // log2e/8
        case 1:  gemm_core(kbf, WkT, bk, Kh,  1, 1.0f);           break;
        default: gemm_core(vbf, WvT, bv, VhT, 2, 1.0f);           break;
    }
}

__global__ __launch_bounds__(256) void out_gemm(
    const unsigned short* __restrict__ X, const unsigned short* __restrict__ WoT,
    const float* __restrict__ bo, float* __restrict__ out)
{
    gemm_core(X, WoT, bo, out, 0, 1.0f);
}

// ---------------------------------------------------------------------------
// Flash attention v6: same layout/swizzle/MFMA structure as v5, but the kt
// loop is manually unrolled x2 so the double-buffer index `cur` is a literal,
// and ALL LDS accesses are ds_read at compile-time immediate offsets
// (cur*8192 + t*2048 / n*2048, max 14336 < 64K) from 6 loop-invariant
// per-lane byte bases (2 for K-frags, 4 for V-frags). Global staging uses two
// incremented pointers instead of per-kt multiplies. QK^T zero-accumulator is
// a loop-invariant register quad instead of 16 v_movs/kt. Theory: v5 was
// VALU-issue-bound (VALUBusy 52% vs MfmaUtil 30%) on per-iteration address
// recomputation (VGPR=52 -> compiler rematerialized everything).
// ---------------------------------------------------------------------------
__global__ __launch_bounds__(256) void attn_kernel(
    const unsigned short* __restrict__ Qh, const unsigned short* __restrict__ Kh,
    const unsigned short* __restrict__ VhT, unsigned short* __restrict__ X)
{
    __shared__ unsigned short Ks[2][64 * 64];
    __shared__ unsigned short Vt[2][64 * 64];

    int tid = threadIdx.x;
    int qb = blockIdx.x & 31, bh = blockIdx.x >> 5;
    int b = bh >> 4, h = bh & 15;
    int lane = tid & 63, wave = tid >> 6;
    int lm = lane & 15, quad = lane >> 4;

    const unsigned short* Kbase = Kh + (size_t)bh * 2048 * 64;
    const unsigned short* Vbase = VhT + (size_t)bh * 64 * 2048;

    int srow = wave * 8 + (lane >> 3);
    int schk = ((lane & 7) ^ ((lane >> 3) & 7)) * 8;
    int swz  = lm & 7;

    // loop-invariant per-lane LDS byte bases; buffer 1 lives at +8192 bytes
    const char* ks0 = (const char*)&Ks[0][0] + lm * 128 + ((quad ^ swz) * 16);
    const char* ks1 = (const char*)&Ks[0][0] + lm * 128 + (((quad + 4) ^ swz) * 16);
    int qh2 = quad >> 1, wo = (quad & 1) * 8;            // bytes
    const char* vt0 = (const char*)&Vt[0][0] + lm * 128 + (((0 + qh2) ^ swz) * 16) + wo;
    const char* vt1 = (const char*)&Vt[0][0] + lm * 128 + (((2 + qh2) ^ swz) * 16) + wo;
    const char* vt2 = (const char*)&Vt[0][0] + lm * 128 + (((4 + qh2) ^ swz) * 16) + wo;
    const char* vt3 = (const char*)&Vt[0][0] + lm * 128 + (((6 + qh2) ^ swz) * 16) + wo;

    // incremented global staging pointers (tile stride: K += 64 rows, V += 64 cols)
    const unsigned short* Kg = Kbase + (size_t)srow * 64 + schk;
    const unsigned short* Vg = Vbase + (size_t)srow * 2048 + schk;

    int qrow = qb * 64 + wave * 16 + lm;
    const unsigned short* qptr = Qh + ((size_t)bh * 2048 + qrow) * 64;
    short8 qf0 = *(const short8*)&qptr[quad * 8];
    short8 qf1 = *(const short8*)&qptr[32 + quad * 8];

    f32x4 o[4];
    for (int n = 0; n < 4; n++)
        for (int r = 0; r < 4; r++) o[n][r] = 0.0f;
    float l = 0.0f;
    f32x4 zf;
    zf[0] = zf[1] = zf[2] = zf[3] = 0.0f;

#define STAGE(BUF) do { \
        GLD16(Kg,             &Ks[BUF][(wave * 8) * 64]); \
        GLD16(Kg + 32 * 64,   &Ks[BUF][(32 + wave * 8) * 64]); \
        GLD16(Vg,             &Vt[BUF][(wave * 8) * 64]); \
        GLD16(Vg + 32 * 2048, &Vt[BUF][(32 + wave * 8) * 64]); \
        Kg += 64 * 64; Vg += 64; } while (0)

#define QKPV(CUR) do { \
        short4v pa[4]; \
        _Pragma("unroll") \
        for (int t = 0; t < 4; t++) { \
            short8 ka0 = *(const short8*)(ks0 + (CUR) * 8192 + t * 2048); \
            short8 ka1 = *(const short8*)(ks1 + (CUR) * 8192 + t * 2048); \
            f32x4 z = __builtin_amdgcn_mfma_f32_16x16x32_bf16(ka0, qf0, zf, 0, 0, 0); \
            z = __builtin_amdgcn_mfma_f32_16x16x32_bf16(ka1, qf1, z, 0, 0, 0); \
            float p0 = __builtin_amdgcn_exp2f(z[0]); \
            float p1 = __builtin_amdgcn_exp2f(z[1]); \
            float p2 = __builtin_amdgcn_exp2f(z[2]); \
            float p3 = __builtin_amdgcn_exp2f(z[3]); \
            l += (p0 + p1) + (p2 + p3); \
            pa[t] = pack4bf(p0, p1, p2, p3); \
        } \
        _Pragma("unroll") \
        for (int n = 0; n < 4; n++) { \
            o[n] = __builtin_amdgcn_mfma_f32_16x16x16bf16_1k(pa[0], \
                *(const short4v*)(vt0 + (CUR) * 8192 + n * 2048), o[n], 0, 0, 0); \
            o[n] = __builtin_amdgcn_mfma_f32_16x16x16bf16_1k(pa[1], \
                *(const short4v*)(vt1 + (CUR) * 8192 + n * 2048), o[n], 0, 0, 0); \
            o[n] = __builtin_amdgcn_mfma_f32_16x16x16bf16_1k(pa[2], \
                *(const short4v*)(vt2 + (CUR) * 8192 + n * 2048), o[n], 0, 0, 0); \
            o[n] = __builtin_amdgcn_mfma_f32_16x16x16bf16_1k(pa[3], \
                *(const short4v*)(vt3 + (CUR) * 8192 + n * 2048), o[n], 0, 0, 0); \
        } } while (0)

    STAGE(0);                    // tile 0 -> buf0
    __syncthreads();

    for (int kt = 0; kt < 32; kt += 2) {
        STAGE(1);                // tile kt+1 -> buf1 (always valid: kt+1 <= 31)
        QKPV(0);                 // compute tile kt from buf0
        __syncthreads();
        if (kt + 2 < 32) STAGE(0);   // tile kt+2 -> buf0
        QKPV(1);                 // compute tile kt+1 from buf1
        __syncthreads();
    }

#undef STAGE
#undef QKPV

    l += __shfl_xor(l, 16);
    l += __shfl_xor(l, 32);
    float inv = 1.0f / l;

    for (int r = 0; r < 4; r++) {
        float invr = __shfl(inv, (lane & 48) | (quad * 4 + r));
        int row = qb * 64 + wave * 16 + quad * 4 + r;
        for (int n = 0; n < 4; n++)
            X[((size_t)b * 2048 + row) * 1024 + h * 64 + n * 16 + lm] = f2bf(o[n][r] * invr);
    }
}

// ---------------------------------------------------------------------------
extern "C" void kernel_launch(void* const* d_in, const int* in_sizes, int n_in,
                              void* d_out, int out_size, void* d_ws, size_t ws_size,
                              hipStream_t stream)
{
    const float* q  = (const float*)d_in[0];
    const float* k  = (const float*)d_in[1];
    const float* v  = (const float*)d_in[2];
    const float* Wq = (const float*)d_in[3];
    const float* bq = (const float*)d_in[4];
    const float* Wk = (const float*)d_in[5];
    const float* bk = (const float*)d_in[6];
    const float* Wv = (const float*)d_in[7];
    const float* bv = (const float*)d_in[8];
    const float* Wo = (const float*)d_in[9];
    const float* bo = (const float*)d_in[10];

    // 40 MB ws layout, sequential aliasing:
    //  0- 4M: WqT,WkT,WvT,WoT (1M elems each)
    //  4- 8M: qbf -> Kh | 8-12M: kbf -> VhT | 12-16M: vbf -> X | 16-20M: Qh
    unsigned short* ws  = (unsigned short*)d_ws;
    const unsigned int M1 = 1u << 20;
    unsigned short* WqT = ws;
    unsigned short* WkT = ws + M1;
    unsigned short* WvT = ws + 2 * M1;
    unsigned short* WoT = ws + 3 * M1;
    unsigned short* qbf = ws + 4 * M1;
    unsigned short* kbf = ws + 8 * M1;
    unsigned short* vbf = ws + 12 * M1;
    unsigned short* Qh  = ws + 16 * M1;
    unsigned short* Kh  = ws + 4 * M1;    // over dead qbf
    unsigned short* VhT = ws + 8 * M1;    // over dead kbf
    unsigned short* X   = ws + 12 * M1;   // over dead vbf

    prep<<<dim3(7168), 256, 0, stream>>>(q, k, v, qbf, kbf, vbf,
                                         Wq, Wk, Wv, Wo, WqT, WkT, WvT, WoT);
    qkv_gemm<<<dim3(32, 8, 3), 256, 0, stream>>>(qbf, kbf, vbf, WqT, WkT, WvT,
                                                 bq, bk, bv, Qh, Kh, VhT);
    attn_kernel<<<dim3(1024), 256, 0, stream>>>(Qh, Kh, VhT, X);
    out_gemm<<<dim3(32, 8), 256, 0, stream>>>(X, WoT, bo, (float*)d_out);
}

// Round 2
// 220.992 us; speedup vs baseline: 1.0709x; 1.0373x over previous
//
#include <hip/hip_runtime.h>
#include <hip/hip_bf16.h>

typedef __attribute__((ext_vector_type(8))) short short8;
typedef __attribute__((ext_vector_type(4))) short short4v;
typedef __attribute__((ext_vector_type(4))) float f32x4;

__device__ __forceinline__ unsigned short f2bf(float f) {
    __hip_bfloat16 h = __float2bfloat16(f);
    unsigned short u;
    __builtin_memcpy(&u, &h, 2);
    return u;
}
// packed RNE f32->bf16 pairs: compiles to v_cvt_pk_bf16_f32
__device__ __forceinline__ short4v pack4bf(float a, float b, float c, float d) {
    union { __hip_bfloat162 h[2]; short4v s; } r;
    r.h[0] = __float22bfloat162_rn(make_float2(a, b));
    r.h[1] = __float22bfloat162_rn(make_float2(c, d));
    return r.s;
}

#define GLD16(gp, lp) __builtin_amdgcn_global_load_lds( \
    (const __attribute__((address_space(1))) void*)(gp), \
    (__attribute__((address_space(3))) void*)(lp), 16, 0, 0)

// ---------------------------------------------------------------------------
// prep: fused f32->bf16 convert of q,k,v (blocks 0..6143) + weight transpose
// (blocks 6144..7167). One launch instead of two.
// ---------------------------------------------------------------------------
__global__ __launch_bounds__(256) void prep(
    const float* __restrict__ q, const float* __restrict__ k, const float* __restrict__ v,
    unsigned short* __restrict__ qb, unsigned short* __restrict__ kb, unsigned short* __restrict__ vb,
    const float* __restrict__ W0, const float* __restrict__ W1,
    const float* __restrict__ W2, const float* __restrict__ W3,
    unsigned short* __restrict__ T0, unsigned short* __restrict__ T1,
    unsigned short* __restrict__ T2, unsigned short* __restrict__ T3)
{
    __shared__ unsigned short Ts[64 * 72];
    int bx = blockIdx.x;
    if (bx < 6144) {
        const float* src; unsigned short* dst;
        switch (bx >> 11) { case 0: src = q; dst = qb; break;
                            case 1: src = k; dst = kb; break;
                            default: src = v; dst = vb; break; }
        size_t i = ((size_t)(bx & 2047) * 256 + threadIdx.x) * 8;
        float4 x0 = *(const float4*)&src[i];
        float4 x1 = *(const float4*)&src[i + 4];
        union { unsigned short s[8]; uint4 u; } p;
        p.s[0] = f2bf(x0.x); p.s[1] = f2bf(x0.y); p.s[2] = f2bf(x0.z); p.s[3] = f2bf(x0.w);
        p.s[4] = f2bf(x1.x); p.s[5] = f2bf(x1.y); p.s[6] = f2bf(x1.z); p.s[7] = f2bf(x1.w);
        *(uint4*)&dst[i] = p.u;
        return;
    }
    int w = bx - 6144;                // 1024 blocks: z(4) x kx(16) x ny(16)
    int z = w >> 8, rem = w & 255;
    int kx = rem >> 4, ny = rem & 15;
    const float* W;
    unsigned short* T;
    switch (z) {
        case 0: W = W0; T = T0; break;
        case 1: W = W1; T = T1; break;
        case 2: W = W2; T = T2; break;
        default: W = W3; T = T3; break;
    }
    int tid = threadIdx.x;
    int c = tid & 7, r = tid >> 3;
    int k0 = kx * 64, n0 = ny * 64;
    for (int i = 0; i < 64; i += 32) {
        const float* src = &W[(size_t)(k0 + r + i) * 1024 + n0 + c * 8];
        float4 x0 = *(const float4*)src;
        float4 x1 = *(const float4*)(src + 4);
        unsigned short* d = &Ts[(r + i) * 72 + c * 8];
        d[0] = f2bf(x0.x); d[1] = f2bf(x0.y); d[2] = f2bf(x0.z); d[3] = f2bf(x0.w);
        d[4] = f2bf(x1.x); d[5] = f2bf(x1.y); d[6] = f2bf(x1.z); d[7] = f2bf(x1.w);
    }
    __syncthreads();
    for (int i = 0; i < 64; i += 32) {
        union { unsigned short s[8]; uint4 v; } u;
        for (int j = 0; j < 8; j++) u.s[j] = Ts[(c * 8 + j) * 72 + (r + i)];
        *(uint4*)&T[(size_t)(n0 + r + i) * 1024 + k0 + c * 8] = u.v;
    }
}

// ---------------------------------------------------------------------------
// GEMM core v3: 128x128 tile, BK=32, single-buffered global_load_lds staging
// + XOR-swizzled LDS (see r0 notes). mode 0: f32 row-major; mode 1: bf16
// [bh][t][d] scatter; mode 2: bf16 [bh][d][t] scatter (packed 8B stores).
// ---------------------------------------------------------------------------
__device__ __forceinline__ void gemm_core(
    const unsigned short* __restrict__ A, const unsigned short* __restrict__ BT,
    const float* __restrict__ bias, void* __restrict__ outv,
    int mode, float scale)
{
    const int K = 1024;
    __shared__ unsigned short As[128 * 32];
    __shared__ unsigned short Bs[128 * 32];
    int tid = threadIdx.x;
    int m0 = blockIdx.x * 128, n0 = blockIdx.y * 128;
    int lane = tid & 63, wave = tid >> 6;
    int lm = lane & 15, quad = lane >> 4;
    int wm = (wave >> 1) * 64, wn = (wave & 1) * 64;

    int lrow = lane >> 2;
    int scol = ((lane & 3) ^ ((lane >> 3) & 3)) * 8;
    const unsigned short* Ag = A + (size_t)(m0 + wave * 32 + lrow) * K + scol;
    const unsigned short* Bg = BT + (size_t)(n0 + wave * 32 + lrow) * K + scol;
    unsigned short* AsW0 = &As[(wave * 32) * 32];
    unsigned short* AsW1 = &As[(wave * 32 + 16) * 32];
    unsigned short* BsW0 = &Bs[(wave * 32) * 32];
    unsigned short* BsW1 = &Bs[(wave * 32 + 16) * 32];

    int rpos = (quad ^ ((lm >> 1) & 3)) * 8;

    f32x4 acc[4][4];
    for (int i = 0; i < 4; i++)
        for (int j = 0; j < 4; j++)
            for (int r = 0; r < 4; r++) acc[i][j][r] = 0.0f;

    for (int kb = 0; kb < K; kb += 32) {
        GLD16(Ag, AsW0);
        GLD16(Ag + 16 * K, AsW1);
        GLD16(Bg, BsW0);
        GLD16(Bg + 16 * K, BsW1);
        Ag += 32; Bg += 32;
        __syncthreads();
        short8 a[4], b[4];
        for (int i = 0; i < 4; i++)
            a[i] = *(const short8*)&As[(wm + i * 16 + lm) * 32 + rpos];
        for (int j = 0; j < 4; j++)
            b[j] = *(const short8*)&Bs[(wn + j * 16 + lm) * 32 + rpos];
        for (int i = 0; i < 4; i++)
            for (int j = 0; j < 4; j++)
                acc[i][j] = __builtin_amdgcn_mfma_f32_16x16x32_bf16(a[i], b[j], acc[i][j], 0, 0, 0);
        __syncthreads();
    }

    for (int j = 0; j < 4; j++) {
        int col = n0 + wn + j * 16 + lm;
        float bv = bias[col];
        for (int i = 0; i < 4; i++) {
            int rowb = m0 + wm + i * 16 + quad * 4;
            if (mode == 0) {
                float* out32 = (float*)outv;
                for (int r = 0; r < 4; r++)
                    out32[(size_t)(rowb + r) * 1024 + col] = (acc[i][j][r] + bv) * scale;
            } else if (mode == 1) {
                unsigned short* out16 = (unsigned short*)outv;
                int h = col >> 6, d = col & 63;
                int bb = rowb >> 11, t = rowb & 2047;
                size_t base = (((size_t)(bb * 16 + h)) * 2048 + t) * 64 + d;
                for (int r = 0; r < 4; r++)
                    out16[base + (size_t)r * 64] = f2bf((acc[i][j][r] + bv) * scale);
            } else {
                unsigned short* out16 = (unsigned short*)outv;
                int h = col >> 6, d = col & 63;
                int bb = rowb >> 11, t = rowb & 2047;   // t is 4-aligned
                ushort4 pk;
                pk.x = f2bf((acc[i][j][0] + bv) * scale);
                pk.y = f2bf((acc[i][j][1] + bv) * scale);
                pk.z = f2bf((acc[i][j][2] + bv) * scale);
                pk.w = f2bf((acc[i][j][3] + bv) * scale);
                *(ushort4*)&out16[(((size_t)(bb * 16 + h)) * 64 + d) * 2048 + t] = pk;
            }
        }
    }
}

// Fused QKV projections: blockIdx.z selects {q,k,v}; 768 blocks = 3/CU.
// Q scale folds 1/sqrt(64) * log2(e) so attention can use exp2 natively.
__global__ __launch_bounds__(256) void qkv_gemm(
    const unsigned short* __restrict__ qbf, const unsigned short* __restrict__ kbf,
    const unsigned short* __restrict__ vbf,
    const unsigned short* __restrict__ WqT, const unsigned short* __restrict__ WkT,
    const unsigned short* __restrict__ WvT,
    const float* __restrict__ bq, const float* __restrict__ bk, const float* __restrict__ bv,
    unsigned short* __restrict__ Qh, unsigned short* __restrict__ Kh,
    unsigned short* __restrict__ VhT)
{
    switch (blockIdx.z) {
        case 0:  gemm_core(qbf, WqT, bq, Qh,  1, 0.18033688011f); break; // log2e/8
        case 1:  gemm_core(kbf, WkT, bk, Kh,  1, 1.0f);           break;
        default: gemm_core(vbf, WvT, bv, VhT, 2, 1.0f);           break;
    }
}

__global__ __launch_bounds__(256) void out_gemm(
    const unsigned short* __restrict__ X, const unsigned short* __restrict__ WoT,
    const float* __restrict__ bo, float* __restrict__ out)
{
    gemm_core(X, WoT, bo, out, 0, 1.0f);
}

// ---------------------------------------------------------------------------
// Flash attention v7: v6 + 2x q-rows per wave (32 instead of 16). Each wave
// now carries TWO Q fragment groups (rows wave*32+lm and +16) and two
// softmax/accumulator states; every K fragment (ds_read_b128) and V fragment
// (ds_read_b64) register load is consumed by BOTH groups' MFMAs. This halves
// LDS read traffic, bank-conflict cycles, and loop/address VALU *per FLOP* —
// the three co-bottlenecks at r1 (LDS ceiling ~1258 TF at 16 FLOP/B, 8.4M
// conflict cycles ~23% of CU time, VALUBusy 43%). Block = 128 q-rows; grid
// 512 = exactly 2 blocks/CU (8 waves/CU, 64 KiB LDS/CU); halved wave count is
// offset by 2x in-wave ILP, and the prefetch->use distance doubles.
// ---------------------------------------------------------------------------
__global__ __launch_bounds__(256) void attn_kernel(
    const unsigned short* __restrict__ Qh, const unsigned short* __restrict__ Kh,
    const unsigned short* __restrict__ VhT, unsigned short* __restrict__ X)
{
    __shared__ unsigned short Ks[2][64 * 64];
    __shared__ unsigned short Vt[2][64 * 64];

    int tid = threadIdx.x;
    int qblk = blockIdx.x & 15, bh = blockIdx.x >> 4;
    int b = bh >> 4, h = bh & 15;
    int lane = tid & 63, wave = tid >> 6;
    int lm = lane & 15, quad = lane >> 4;

    const unsigned short* Kbase = Kh + (size_t)bh * 2048 * 64;
    const unsigned short* Vbase = VhT + (size_t)bh * 64 * 2048;

    int srow = wave * 8 + (lane >> 3);
    int schk = ((lane & 7) ^ ((lane >> 3) & 7)) * 8;
    int swz  = lm & 7;

    // loop-invariant per-lane LDS byte bases; buffer 1 lives at +8192 bytes
    const char* ks0 = (const char*)&Ks[0][0] + lm * 128 + ((quad ^ swz) * 16);
    const char* ks1 = (const char*)&Ks[0][0] + lm * 128 + (((quad + 4) ^ swz) * 16);
    int qh2 = quad >> 1, wo = (quad & 1) * 8;            // bytes
    const char* vt0 = (const char*)&Vt[0][0] + lm * 128 + (((0 + qh2) ^ swz) * 16) + wo;
    const char* vt1 = (const char*)&Vt[0][0] + lm * 128 + (((2 + qh2) ^ swz) * 16) + wo;
    const char* vt2 = (const char*)&Vt[0][0] + lm * 128 + (((4 + qh2) ^ swz) * 16) + wo;
    const char* vt3 = (const char*)&Vt[0][0] + lm * 128 + (((6 + qh2) ^ swz) * 16) + wo;

    // incremented global staging pointers (tile stride: K += 64 rows, V += 64 cols)
    const unsigned short* Kg = Kbase + (size_t)srow * 64 + schk;
    const unsigned short* Vg = Vbase + (size_t)srow * 2048 + schk;

    // two q-row groups per wave: rows qblk*128 + wave*32 + lm (+16)
    int qrow = qblk * 128 + wave * 32 + lm;
    const unsigned short* qptr = Qh + ((size_t)bh * 2048 + qrow) * 64;
    short8 qfa0 = *(const short8*)&qptr[quad * 8];
    short8 qfa1 = *(const short8*)&qptr[32 + quad * 8];
    short8 qfb0 = *(const short8*)&qptr[16 * 64 + quad * 8];
    short8 qfb1 = *(const short8*)&qptr[16 * 64 + 32 + quad * 8];

    f32x4 oA[4], oB[4];
    for (int n = 0; n < 4; n++)
        for (int r = 0; r < 4; r++) { oA[n][r] = 0.0f; oB[n][r] = 0.0f; }
    float lA = 0.0f, lB = 0.0f;
    f32x4 zf;
    zf[0] = zf[1] = zf[2] = zf[3] = 0.0f;

#define STAGE(BUF) do { \
        GLD16(Kg,             &Ks[BUF][(wave * 8) * 64]); \
        GLD16(Kg + 32 * 64,   &Ks[BUF][(32 + wave * 8) * 64]); \
        GLD16(Vg,             &Vt[BUF][(wave * 8) * 64]); \
        GLD16(Vg + 32 * 2048, &Vt[BUF][(32 + wave * 8) * 64]); \
        Kg += 64 * 64; Vg += 64; } while (0)

#define QKPV(CUR) do { \
        short4v pa[4], pb[4]; \
        _Pragma("unroll") \
        for (int t = 0; t < 4; t++) { \
            short8 ka0 = *(const short8*)(ks0 + (CUR) * 8192 + t * 2048); \
            short8 ka1 = *(const short8*)(ks1 + (CUR) * 8192 + t * 2048); \
            f32x4 za = __builtin_amdgcn_mfma_f32_16x16x32_bf16(ka0, qfa0, zf, 0, 0, 0); \
            za = __builtin_amdgcn_mfma_f32_16x16x32_bf16(ka1, qfa1, za, 0, 0, 0); \
            f32x4 zb = __builtin_amdgcn_mfma_f32_16x16x32_bf16(ka0, qfb0, zf, 0, 0, 0); \
            zb = __builtin_amdgcn_mfma_f32_16x16x32_bf16(ka1, qfb1, zb, 0, 0, 0); \
            float a0 = __builtin_amdgcn_exp2f(za[0]); \
            float a1 = __builtin_amdgcn_exp2f(za[1]); \
            float a2 = __builtin_amdgcn_exp2f(za[2]); \
            float a3 = __builtin_amdgcn_exp2f(za[3]); \
            lA += (a0 + a1) + (a2 + a3); \
            pa[t] = pack4bf(a0, a1, a2, a3); \
            float b0 = __builtin_amdgcn_exp2f(zb[0]); \
            float b1 = __builtin_amdgcn_exp2f(zb[1]); \
            float b2 = __builtin_amdgcn_exp2f(zb[2]); \
            float b3 = __builtin_amdgcn_exp2f(zb[3]); \
            lB += (b0 + b1) + (b2 + b3); \
            pb[t] = pack4bf(b0, b1, b2, b3); \
        } \
        _Pragma("unroll") \
        for (int n = 0; n < 4; n++) { \
            short4v v0 = *(const short4v*)(vt0 + (CUR) * 8192 + n * 2048); \
            short4v v1 = *(const short4v*)(vt1 + (CUR) * 8192 + n * 2048); \
            short4v v2 = *(const short4v*)(vt2 + (CUR) * 8192 + n * 2048); \
            short4v v3 = *(const short4v*)(vt3 + (CUR) * 8192 + n * 2048); \
            oA[n] = __builtin_amdgcn_mfma_f32_16x16x16bf16_1k(pa[0], v0, oA[n], 0, 0, 0); \
            oB[n] = __builtin_amdgcn_mfma_f32_16x16x16bf16_1k(pb[0], v0, oB[n], 0, 0, 0); \
            oA[n] = __builtin_amdgcn_mfma_f32_16x16x16bf16_1k(pa[1], v1, oA[n], 0, 0, 0); \
            oB[n] = __builtin_amdgcn_mfma_f32_16x16x16bf16_1k(pb[1], v1, oB[n], 0, 0, 0); \
            oA[n] = __builtin_amdgcn_mfma_f32_16x16x16bf16_1k(pa[2], v2, oA[n], 0, 0, 0); \
            oB[n] = __builtin_amdgcn_mfma_f32_16x16x16bf16_1k(pb[2], v2, oB[n], 0, 0, 0); \
            oA[n] = __builtin_amdgcn_mfma_f32_16x16x16bf16_1k(pa[3], v3, oA[n], 0, 0, 0); \
            oB[n] = __builtin_amdgcn_mfma_f32_16x16x16bf16_1k(pb[3], v3, oB[n], 0, 0, 0); \
        } } while (0)

    STAGE(0);                    // tile 0 -> buf0
    __syncthreads();

    for (int kt = 0; kt < 32; kt += 2) {
        STAGE(1);                // tile kt+1 -> buf1 (always valid: kt+1 <= 31)
        QKPV(0);                 // compute tile kt from buf0
        __syncthreads();
        if (kt + 2 < 32) STAGE(0);   // tile kt+2 -> buf0
        QKPV(1);                 // compute tile kt+1 from buf1
        __syncthreads();
    }

#undef STAGE
#undef QKPV

    lA += __shfl_xor(lA, 16);
    lA += __shfl_xor(lA, 32);
    lB += __shfl_xor(lB, 16);
    lB += __shfl_xor(lB, 32);
    float invA = 1.0f / lA;
    float invB = 1.0f / lB;

    for (int r = 0; r < 4; r++) {
        int src = (lane & 48) | (quad * 4 + r);
        float invAr = __shfl(invA, src);
        float invBr = __shfl(invB, src);
        int rowA = qblk * 128 + wave * 32 + quad * 4 + r;
        for (int n = 0; n < 4; n++) {
            X[((size_t)b * 2048 + rowA) * 1024 + h * 64 + n * 16 + lm] = f2bf(oA[n][r] * invAr);
            X[((size_t)b * 2048 + rowA + 16) * 1024 + h * 64 + n * 16 + lm] = f2bf(oB[n][r] * invBr);
        }
    }
}

// ---------------------------------------------------------------------------
extern "C" void kernel_launch(void* const* d_in, const int* in_sizes, int n_in,
                              void* d_out, int out_size, void* d_ws, size_t ws_size,
                              hipStream_t stream)
{
    const float* q  = (const float*)d_in[0];
    const float* k  = (const float*)d_in[1];
    const float* v  = (const float*)d_in[2];
    const float* Wq = (const float*)d_in[3];
    const float* bq = (const float*)d_in[4];
    const float* Wk = (const float*)d_in[5];
    const float* bk = (const float*)d_in[6];
    const float* Wv = (const float*)d_in[7];
    const float* bv = (const float*)d_in[8];
    const float* Wo = (const float*)d_in[9];
    const float* bo = (const float*)d_in[10];

    // 40 MB ws layout, sequential aliasing:
    //  0- 4M: WqT,WkT,WvT,WoT (1M elems each)
    //  4- 8M: qbf -> Kh | 8-12M: kbf -> VhT | 12-16M: vbf -> X | 16-20M: Qh
    unsigned short* ws  = (unsigned short*)d_ws;
    const unsigned int M1 = 1u << 20;
    unsigned short* WqT = ws;
    unsigned short* WkT = ws + M1;
    unsigned short* WvT = ws + 2 * M1;
    unsigned short* WoT = ws + 3 * M1;
    unsigned short* qbf = ws + 4 * M1;
    unsigned short* kbf = ws + 8 * M1;
    unsigned short* vbf = ws + 12 * M1;
    unsigned short* Qh  = ws + 16 * M1;
    unsigned short* Kh  = ws + 4 * M1;    // over dead qbf
    unsigned short* VhT = ws + 8 * M1;    // over dead kbf
    unsigned short* X   = ws + 12 * M1;   // over dead vbf

    prep<<<dim3(7168), 256, 0, stream>>>(q, k, v, qbf, kbf, vbf,
                                         Wq, Wk, Wv, Wo, WqT, WkT, WvT, WoT);
    qkv_gemm<<<dim3(32, 8, 3), 256, 0, stream>>>(qbf, kbf, vbf, WqT, WkT, WvT,
                                                 bq, bk, bv, Qh, Kh, VhT);
    attn_kernel<<<dim3(512), 256, 0, stream>>>(Qh, Kh, VhT, X);
    out_gemm<<<dim3(32, 8), 256, 0, stream>>>(X, WoT, bo, (float*)d_out);
}

// Round 3
// 220.287 us; speedup vs baseline: 1.0743x; 1.0032x over previous
//
#include <hip/hip_runtime.h>
#include <hip/hip_bf16.h>

typedef __attribute__((ext_vector_type(8))) short short8;
typedef __attribute__((ext_vector_type(4))) short short4v;
typedef __attribute__((ext_vector_type(4))) float f32x4;

__device__ __forceinline__ unsigned short f2bf(float f) {
    __hip_bfloat16 h = __float2bfloat16(f);
    unsigned short u;
    __builtin_memcpy(&u, &h, 2);
    return u;
}
// packed RNE f32->bf16 pairs: compiles to v_cvt_pk_bf16_f32
__device__ __forceinline__ short4v pack4bf(float a, float b, float c, float d) {
    union { __hip_bfloat162 h[2]; short4v s; } r;
    r.h[0] = __float22bfloat162_rn(make_float2(a, b));
    r.h[1] = __float22bfloat162_rn(make_float2(c, d));
    return r.s;
}

#define GLD16(gp, lp) __builtin_amdgcn_global_load_lds( \
    (const __attribute__((address_space(1))) void*)(gp), \
    (__attribute__((address_space(3))) void*)(lp), 16, 0, 0)

// ---------------------------------------------------------------------------
// prep: fused f32->bf16 convert of q,k,v (blocks 0..6143) + weight transpose
// (blocks 6144..7167). One launch instead of two.
// ---------------------------------------------------------------------------
__global__ __launch_bounds__(256) void prep(
    const float* __restrict__ q, const float* __restrict__ k, const float* __restrict__ v,
    unsigned short* __restrict__ qb, unsigned short* __restrict__ kb, unsigned short* __restrict__ vb,
    const float* __restrict__ W0, const float* __restrict__ W1,
    const float* __restrict__ W2, const float* __restrict__ W3,
    unsigned short* __restrict__ T0, unsigned short* __restrict__ T1,
    unsigned short* __restrict__ T2, unsigned short* __restrict__ T3)
{
    __shared__ unsigned short Ts[64 * 72];
    int bx = blockIdx.x;
    if (bx < 6144) {
        const float* src; unsigned short* dst;
        switch (bx >> 11) { case 0: src = q; dst = qb; break;
                            case 1: src = k; dst = kb; break;
                            default: src = v; dst = vb; break; }
        size_t i = ((size_t)(bx & 2047) * 256 + threadIdx.x) * 8;
        float4 x0 = *(const float4*)&src[i];
        float4 x1 = *(const float4*)&src[i + 4];
        union { unsigned short s[8]; uint4 u; } p;
        p.s[0] = f2bf(x0.x); p.s[1] = f2bf(x0.y); p.s[2] = f2bf(x0.z); p.s[3] = f2bf(x0.w);
        p.s[4] = f2bf(x1.x); p.s[5] = f2bf(x1.y); p.s[6] = f2bf(x1.z); p.s[7] = f2bf(x1.w);
        *(uint4*)&dst[i] = p.u;
        return;
    }
    int w = bx - 6144;                // 1024 blocks: z(4) x kx(16) x ny(16)
    int z = w >> 8, rem = w & 255;
    int kx = rem >> 4, ny = rem & 15;
    const float* W;
    unsigned short* T;
    switch (z) {
        case 0: W = W0; T = T0; break;
        case 1: W = W1; T = T1; break;
        case 2: W = W2; T = T2; break;
        default: W = W3; T = T3; break;
    }
    int tid = threadIdx.x;
    int c = tid & 7, r = tid >> 3;
    int k0 = kx * 64, n0 = ny * 64;
    for (int i = 0; i < 64; i += 32) {
        const float* src = &W[(size_t)(k0 + r + i) * 1024 + n0 + c * 8];
        float4 x0 = *(const float4*)src;
        float4 x1 = *(const float4*)(src + 4);
        unsigned short* d = &Ts[(r + i) * 72 + c * 8];
        d[0] = f2bf(x0.x); d[1] = f2bf(x0.y); d[2] = f2bf(x0.z); d[3] = f2bf(x0.w);
        d[4] = f2bf(x1.x); d[5] = f2bf(x1.y); d[6] = f2bf(x1.z); d[7] = f2bf(x1.w);
    }
    __syncthreads();
    for (int i = 0; i < 64; i += 32) {
        union { unsigned short s[8]; uint4 v; } u;
        for (int j = 0; j < 8; j++) u.s[j] = Ts[(c * 8 + j) * 72 + (r + i)];
        *(uint4*)&T[(size_t)(n0 + r + i) * 1024 + k0 + c * 8] = u.v;
    }
}

// ---------------------------------------------------------------------------
// GEMM core v3: 128x128 tile, BK=32, single-buffered global_load_lds staging
// + XOR-swizzled LDS (see r0 notes). mode 0: f32 row-major; mode 1: bf16
// [bh][t][d] scatter; mode 2: bf16 [bh][d][t] scatter (packed 8B stores).
// ---------------------------------------------------------------------------
__device__ __forceinline__ void gemm_core(
    const unsigned short* __restrict__ A, const unsigned short* __restrict__ BT,
    const float* __restrict__ bias, void* __restrict__ outv,
    int mode, float scale)
{
    const int K = 1024;
    __shared__ unsigned short As[128 * 32];
    __shared__ unsigned short Bs[128 * 32];
    int tid = threadIdx.x;
    int m0 = blockIdx.x * 128, n0 = blockIdx.y * 128;
    int lane = tid & 63, wave = tid >> 6;
    int lm = lane & 15, quad = lane >> 4;
    int wm = (wave >> 1) * 64, wn = (wave & 1) * 64;

    int lrow = lane >> 2;
    int scol = ((lane & 3) ^ ((lane >> 3) & 3)) * 8;
    const unsigned short* Ag = A + (size_t)(m0 + wave * 32 + lrow) * K + scol;
    const unsigned short* Bg = BT + (size_t)(n0 + wave * 32 + lrow) * K + scol;
    unsigned short* AsW0 = &As[(wave * 32) * 32];
    unsigned short* AsW1 = &As[(wave * 32 + 16) * 32];
    unsigned short* BsW0 = &Bs[(wave * 32) * 32];
    unsigned short* BsW1 = &Bs[(wave * 32 + 16) * 32];

    int rpos = (quad ^ ((lm >> 1) & 3)) * 8;

    f32x4 acc[4][4];
    for (int i = 0; i < 4; i++)
        for (int j = 0; j < 4; j++)
            for (int r = 0; r < 4; r++) acc[i][j][r] = 0.0f;

    for (int kb = 0; kb < K; kb += 32) {
        GLD16(Ag, AsW0);
        GLD16(Ag + 16 * K, AsW1);
        GLD16(Bg, BsW0);
        GLD16(Bg + 16 * K, BsW1);
        Ag += 32; Bg += 32;
        __syncthreads();
        short8 a[4], b[4];
        for (int i = 0; i < 4; i++)
            a[i] = *(const short8*)&As[(wm + i * 16 + lm) * 32 + rpos];
        for (int j = 0; j < 4; j++)
            b[j] = *(const short8*)&Bs[(wn + j * 16 + lm) * 32 + rpos];
        for (int i = 0; i < 4; i++)
            for (int j = 0; j < 4; j++)
                acc[i][j] = __builtin_amdgcn_mfma_f32_16x16x32_bf16(a[i], b[j], acc[i][j], 0, 0, 0);
        __syncthreads();
    }

    for (int j = 0; j < 4; j++) {
        int col = n0 + wn + j * 16 + lm;
        float bv = bias[col];
        for (int i = 0; i < 4; i++) {
            int rowb = m0 + wm + i * 16 + quad * 4;
            if (mode == 0) {
                float* out32 = (float*)outv;
                for (int r = 0; r < 4; r++)
                    out32[(size_t)(rowb + r) * 1024 + col] = (acc[i][j][r] + bv) * scale;
            } else if (mode == 1) {
                unsigned short* out16 = (unsigned short*)outv;
                int h = col >> 6, d = col & 63;
                int bb = rowb >> 11, t = rowb & 2047;
                size_t base = (((size_t)(bb * 16 + h)) * 2048 + t) * 64 + d;
                for (int r = 0; r < 4; r++)
                    out16[base + (size_t)r * 64] = f2bf((acc[i][j][r] + bv) * scale);
            } else {
                unsigned short* out16 = (unsigned short*)outv;
                int h = col >> 6, d = col & 63;
                int bb = rowb >> 11, t = rowb & 2047;   // t is 4-aligned
                ushort4 pk;
                pk.x = f2bf((acc[i][j][0] + bv) * scale);
                pk.y = f2bf((acc[i][j][1] + bv) * scale);
                pk.z = f2bf((acc[i][j][2] + bv) * scale);
                pk.w = f2bf((acc[i][j][3] + bv) * scale);
                *(ushort4*)&out16[(((size_t)(bb * 16 + h)) * 64 + d) * 2048 + t] = pk;
            }
        }
    }
}

// Fused QKV projections: blockIdx.z selects {q,k,v}; 768 blocks = 3/CU.
// Q scale folds 1/sqrt(64) * log2(e) so attention can use exp2 natively.
__global__ __launch_bounds__(256) void qkv_gemm(
    const unsigned short* __restrict__ qbf, const unsigned short* __restrict__ kbf,
    const unsigned short* __restrict__ vbf,
    const unsigned short* __restrict__ WqT, const unsigned short* __restrict__ WkT,
    const unsigned short* __restrict__ WvT,
    const float* __restrict__ bq, const float* __restrict__ bk, const float* __restrict__ bv,
    unsigned short* __restrict__ Qh, unsigned short* __restrict__ Kh,
    unsigned short* __restrict__ VhT)
{
    switch (blockIdx.z) {
        case 0:  gemm_core(qbf, WqT, bq, Qh,  1, 0.18033688011f); break; // log2e/8
        case 1:  gemm_core(kbf, WkT, bk, Kh,  1, 1.0f);           break;
        default: gemm_core(vbf, WvT, bv, VhT, 2, 1.0f);           break;
    }
}

__global__ __launch_bounds__(256) void out_gemm(
    const unsigned short* __restrict__ X, const unsigned short* __restrict__ WoT,
    const float* __restrict__ bo, float* __restrict__ out)
{
    gemm_core(X, WoT, bo, out, 0, 1.0f);
}

// ---------------------------------------------------------------------------
// Flash attention v8: v7's 2x q-rows/wave compute (LDS traffic and conflict
// amortization kept) + T3/T4-style deep pipeline to fix v7's latency
// exposure at 2 waves/SIMD: 4 LDS buffers, depth-3 prefetch, raw s_barrier
// with counted s_waitcnt vmcnt(8) (never 0 in the loop). Prologue stages
// tiles 0-2 (12 loads in flight); each iter retires only tile t's 4 loads,
// keeps 8 in flight ACROSS the barrier, stages t+3 into buf (t+3)%4 (safe:
// that buf's readers all retired their lgkmcnt-waited ds_reads before
// passing barrier t). Q-fragment global loads are vmcnt(0)-drained once
// before the prologue so the in-loop vmcnt counts only staging loads.
// Rule-18 fencing: "memory"-clobbered asm + sched_barrier(0) per phase.
// ---------------------------------------------------------------------------
__global__ __launch_bounds__(256) void attn_kernel(
    const unsigned short* __restrict__ Qh, const unsigned short* __restrict__ Kh,
    const unsigned short* __restrict__ VhT, unsigned short* __restrict__ X)
{
    __shared__ unsigned short Ks[4][64 * 64];
    __shared__ unsigned short Vt[4][64 * 64];

    int tid = threadIdx.x;
    int qblk = blockIdx.x & 15, bh = blockIdx.x >> 4;
    int b = bh >> 4, h = bh & 15;
    int lane = tid & 63, wave = tid >> 6;
    int lm = lane & 15, quad = lane >> 4;

    const unsigned short* Kbase = Kh + (size_t)bh * 2048 * 64;
    const unsigned short* Vbase = VhT + (size_t)bh * 64 * 2048;

    int srow = wave * 8 + (lane >> 3);
    int schk = ((lane & 7) ^ ((lane >> 3) & 7)) * 8;
    int swz  = lm & 7;

    // loop-invariant per-lane LDS byte bases; buffer i lives at +i*8192 bytes
    const char* ks0 = (const char*)&Ks[0][0] + lm * 128 + ((quad ^ swz) * 16);
    const char* ks1 = (const char*)&Ks[0][0] + lm * 128 + (((quad + 4) ^ swz) * 16);
    int qh2 = quad >> 1, wo = (quad & 1) * 8;            // bytes
    const char* vt0 = (const char*)&Vt[0][0] + lm * 128 + (((0 + qh2) ^ swz) * 16) + wo;
    const char* vt1 = (const char*)&Vt[0][0] + lm * 128 + (((2 + qh2) ^ swz) * 16) + wo;
    const char* vt2 = (const char*)&Vt[0][0] + lm * 128 + (((4 + qh2) ^ swz) * 16) + wo;
    const char* vt3 = (const char*)&Vt[0][0] + lm * 128 + (((6 + qh2) ^ swz) * 16) + wo;

    // incremented global staging pointers (tile stride: K += 64 rows, V += 64 cols)
    const unsigned short* Kg = Kbase + (size_t)srow * 64 + schk;
    const unsigned short* Vg = Vbase + (size_t)srow * 2048 + schk;

    // two q-row groups per wave: rows qblk*128 + wave*32 + lm (+16)
    int qrow = qblk * 128 + wave * 32 + lm;
    const unsigned short* qptr = Qh + ((size_t)bh * 2048 + qrow) * 64;
    short8 qfa0 = *(const short8*)&qptr[quad * 8];
    short8 qfa1 = *(const short8*)&qptr[32 + quad * 8];
    short8 qfb0 = *(const short8*)&qptr[16 * 64 + quad * 8];
    short8 qfb1 = *(const short8*)&qptr[16 * 64 + 32 + quad * 8];
    // drain Q loads so in-loop vmcnt counts ONLY the 4-per-tile staging loads
    asm volatile("s_waitcnt vmcnt(0)" ::: "memory");

    f32x4 oA[4], oB[4];
    for (int n = 0; n < 4; n++)
        for (int r = 0; r < 4; r++) { oA[n][r] = 0.0f; oB[n][r] = 0.0f; }
    float lA = 0.0f, lB = 0.0f;
    f32x4 zf;
    zf[0] = zf[1] = zf[2] = zf[3] = 0.0f;

#define STAGE(BUF) do { \
        GLD16(Kg,             &Ks[BUF][(wave * 8) * 64]); \
        GLD16(Kg + 32 * 64,   &Ks[BUF][(32 + wave * 8) * 64]); \
        GLD16(Vg,             &Vt[BUF][(wave * 8) * 64]); \
        GLD16(Vg + 32 * 2048, &Vt[BUF][(32 + wave * 8) * 64]); \
        Kg += 64 * 64; Vg += 64; } while (0)

#define PHASE(WAITN) do { \
        asm volatile("s_waitcnt vmcnt(" #WAITN ")" ::: "memory"); \
        __builtin_amdgcn_s_barrier(); \
        asm volatile("" ::: "memory"); \
        __builtin_amdgcn_sched_barrier(0); } while (0)

#define QKPV(CUR) do { \
        short4v pa[4], pb[4]; \
        _Pragma("unroll") \
        for (int t = 0; t < 4; t++) { \
            short8 ka0 = *(const short8*)(ks0 + (CUR) * 8192 + t * 2048); \
            short8 ka1 = *(const short8*)(ks1 + (CUR) * 8192 + t * 2048); \
            f32x4 za = __builtin_amdgcn_mfma_f32_16x16x32_bf16(ka0, qfa0, zf, 0, 0, 0); \
            za = __builtin_amdgcn_mfma_f32_16x16x32_bf16(ka1, qfa1, za, 0, 0, 0); \
            f32x4 zb = __builtin_amdgcn_mfma_f32_16x16x32_bf16(ka0, qfb0, zf, 0, 0, 0); \
            zb = __builtin_amdgcn_mfma_f32_16x16x32_bf16(ka1, qfb1, zb, 0, 0, 0); \
            float a0 = __builtin_amdgcn_exp2f(za[0]); \
            float a1 = __builtin_amdgcn_exp2f(za[1]); \
            float a2 = __builtin_amdgcn_exp2f(za[2]); \
            float a3 = __builtin_amdgcn_exp2f(za[3]); \
            lA += (a0 + a1) + (a2 + a3); \
            pa[t] = pack4bf(a0, a1, a2, a3); \
            float b0 = __builtin_amdgcn_exp2f(zb[0]); \
            float b1 = __builtin_amdgcn_exp2f(zb[1]); \
            float b2 = __builtin_amdgcn_exp2f(zb[2]); \
            float b3 = __builtin_amdgcn_exp2f(zb[3]); \
            lB += (b0 + b1) + (b2 + b3); \
            pb[t] = pack4bf(b0, b1, b2, b3); \
        } \
        _Pragma("unroll") \
        for (int n = 0; n < 4; n++) { \
            short4v v0 = *(const short4v*)(vt0 + (CUR) * 8192 + n * 2048); \
            short4v v1 = *(const short4v*)(vt1 + (CUR) * 8192 + n * 2048); \
            short4v v2 = *(const short4v*)(vt2 + (CUR) * 8192 + n * 2048); \
            short4v v3 = *(const short4v*)(vt3 + (CUR) * 8192 + n * 2048); \
            oA[n] = __builtin_amdgcn_mfma_f32_16x16x16bf16_1k(pa[0], v0, oA[n], 0, 0, 0); \
            oB[n] = __builtin_amdgcn_mfma_f32_16x16x16bf16_1k(pb[0], v0, oB[n], 0, 0, 0); \
            oA[n] = __builtin_amdgcn_mfma_f32_16x16x16bf16_1k(pa[1], v1, oA[n], 0, 0, 0); \
            oB[n] = __builtin_amdgcn_mfma_f32_16x16x16bf16_1k(pb[1], v1, oB[n], 0, 0, 0); \
            oA[n] = __builtin_amdgcn_mfma_f32_16x16x16bf16_1k(pa[2], v2, oA[n], 0, 0, 0); \
            oB[n] = __builtin_amdgcn_mfma_f32_16x16x16bf16_1k(pb[2], v2, oB[n], 0, 0, 0); \
            oA[n] = __builtin_amdgcn_mfma_f32_16x16x16bf16_1k(pa[3], v3, oA[n], 0, 0, 0); \
            oB[n] = __builtin_amdgcn_mfma_f32_16x16x16bf16_1k(pb[3], v3, oB[n], 0, 0, 0); \
        } } while (0)

    // prologue: tiles 0,1,2 in flight (12 loads)
    STAGE(0); STAGE(1); STAGE(2);

    // t = 0..27: wait tile t (vmcnt 12->8), stage tile t+3, compute tile t
    for (int u = 0; u < 7; u++) {
        PHASE(8); STAGE(3); QKPV(0);
        PHASE(8); STAGE(0); QKPV(1);
        PHASE(8); STAGE(1); QKPV(2);
        PHASE(8); STAGE(2); QKPV(3);
    }
    // t = 28: stage tile 31; t = 29..31: drain
    PHASE(8); STAGE(3); QKPV(0);
    PHASE(8); QKPV(1);
    PHASE(4); QKPV(2);
    PHASE(0); QKPV(3);

#undef STAGE
#undef PHASE
#undef QKPV

    lA += __shfl_xor(lA, 16);
    lA += __shfl_xor(lA, 32);
    lB += __shfl_xor(lB, 16);
    lB += __shfl_xor(lB, 32);
    float invA = 1.0f / lA;
    float invB = 1.0f / lB;

    for (int r = 0; r < 4; r++) {
        int src = (lane & 48) | (quad * 4 + r);
        float invAr = __shfl(invA, src);
        float invBr = __shfl(invB, src);
        int rowA = qblk * 128 + wave * 32 + quad * 4 + r;
        for (int n = 0; n < 4; n++) {
            X[((size_t)b * 2048 + rowA) * 1024 + h * 64 + n * 16 + lm] = f2bf(oA[n][r] * invAr);
            X[((size_t)b * 2048 + rowA + 16) * 1024 + h * 64 + n * 16 + lm] = f2bf(oB[n][r] * invBr);
        }
    }
}

// ---------------------------------------------------------------------------
extern "C" void kernel_launch(void* const* d_in, const int* in_sizes, int n_in,
                              void* d_out, int out_size, void* d_ws, size_t ws_size,
                              hipStream_t stream)
{
    const float* q  = (const float*)d_in[0];
    const float* k  = (const float*)d_in[1];
    const float* v  = (const float*)d_in[2];
    const float* Wq = (const float*)d_in[3];
    const float* bq = (const float*)d_in[4];
    const float* Wk = (const float*)d_in[5];
    const float* bk = (const float*)d_in[6];
    const float* Wv = (const float*)d_in[7];
    const float* bv = (const float*)d_in[8];
    const float* Wo = (const float*)d_in[9];
    const float* bo = (const float*)d_in[10];

    // 40 MB ws layout, sequential aliasing:
    //  0- 4M: WqT,WkT,WvT,WoT (1M elems each)
    //  4- 8M: qbf -> Kh | 8-12M: kbf -> VhT | 12-16M: vbf -> X | 16-20M: Qh
    unsigned short* ws  = (unsigned short*)d_ws;
    const unsigned int M1 = 1u << 20;
    unsigned short* WqT = ws;
    unsigned short* WkT = ws + M1;
    unsigned short* WvT = ws + 2 * M1;
    unsigned short* WoT = ws + 3 * M1;
    unsigned short* qbf = ws + 4 * M1;
    unsigned short* kbf = ws + 8 * M1;
    unsigned short* vbf = ws + 12 * M1;
    unsigned short* Qh  = ws + 16 * M1;
    unsigned short* Kh  = ws + 4 * M1;    // over dead qbf
    unsigned short* VhT = ws + 8 * M1;    // over dead kbf
    unsigned short* X   = ws + 12 * M1;   // over dead vbf

    prep<<<dim3(7168), 256, 0, stream>>>(q, k, v, qbf, kbf, vbf,
                                         Wq, Wk, Wv, Wo, WqT, WkT, WvT, WoT);
    qkv_gemm<<<dim3(32, 8, 3), 256, 0, stream>>>(qbf, kbf, vbf, WqT, WkT, WvT,
                                                 bq, bk, bv, Qh, Kh, VhT);
    attn_kernel<<<dim3(512), 256, 0, stream>>>(Qh, Kh, VhT, X);
    out_gemm<<<dim3(32, 8), 256, 0, stream>>>(X, WoT, bo, (float*)d_out);
}